// Round 9
// baseline (2240.979 us; speedup 1.0000x reference)
//
#include <hip/hip_runtime.h>
#include <hip/hip_bf16.h>
#include <stdint.h>

#define T_TOK 4096
#define DIM   1024
#define HID   4096
#define NEXP  8
#define NSLOT (T_TOK * 2)
#define KSPLIT 2
#define KS_LEN (HID / KSPLIT)
#define MAXMT 72                 // max sum of ceil(cnt_e/128) = 8192/128 + 8
#define GRID1 (8 * 4 * MAXMT)    // 2304: per XCD, 4 nt-groups x MAXMT mtiles
#define GRID2 (8 * 2 * MAXMT)    // 1152: per XCD, 2 (nt,ks)-groups x MAXMT mtiles

typedef __attribute__((ext_vector_type(8))) short bf16x8;
typedef __attribute__((ext_vector_type(4))) float f32x4;

#define AS1(p) ((const __attribute__((address_space(1))) void*)(p))
#define AS3(p) ((__attribute__((address_space(3))) void*)(p))

static __device__ __forceinline__ unsigned short f2bf(float f) {
    unsigned int u = __float_as_uint(f);
    unsigned int r = (u + 0x7fffu + ((u >> 16) & 1u)) >> 16;
    return (unsigned short)r;
}

static __device__ __forceinline__ f32x4 mfma16(bf16x8 a, bf16x8 b, f32x4 c) {
    return __builtin_amdgcn_mfma_f32_16x16x32_bf16(a, b, c, 0, 0, 0);
}

// ---------------- transpose+convert: src [E][R][C] fp32 -> dst [E][C][R] bf16 ----------------

__global__ __launch_bounds__(256) void transpose_conv_kernel(
    const float* __restrict__ src, unsigned short* __restrict__ dst, int R, int C) {
    __shared__ float tile[64][65];
    int e  = blockIdx.z;
    int r0 = blockIdx.y << 6, c0 = blockIdx.x << 6;
    int tx = threadIdx.x & 15;          // 16 lanes x float4 = 64 cols
    int ty = threadIdx.x >> 4;          // 16 rows per pass
    const float* s = src + (size_t)e * R * C;
    unsigned short* d = dst + (size_t)e * C * R;
#pragma unroll
    for (int q = 0; q < 4; ++q) {
        int r = ty + q * 16;
        float4 v = *(const float4*)(s + (size_t)(r0 + r) * C + c0 + tx * 4);
        tile[r][tx * 4 + 0] = v.x; tile[r][tx * 4 + 1] = v.y;
        tile[r][tx * 4 + 2] = v.z; tile[r][tx * 4 + 3] = v.w;
    }
    __syncthreads();
#pragma unroll
    for (int q = 0; q < 4; ++q) {
        int c = ty + q * 16;            // tile-local col; output row = c0 + c
        ushort4 o;
        o.x = f2bf(tile[tx * 4 + 0][c]);
        o.y = f2bf(tile[tx * 4 + 1][c]);
        o.z = f2bf(tile[tx * 4 + 2][c]);
        o.w = f2bf(tile[tx * 4 + 3][c]);
        *(ushort4*)(d + (size_t)(c0 + c) * R + r0 + tx * 4) = o;
    }
}

// ---------------- routing (fused x->bf16 conversion) ----------------

__global__ __launch_bounds__(256) void router_kernel(
    const float* __restrict__ x, const float* __restrict__ rw,
    const float* __restrict__ rb, unsigned short* __restrict__ xb,
    int* __restrict__ top_i, float* __restrict__ top_w, int* __restrict__ counts) {
    int t = blockIdx.x * 4 + (threadIdx.x >> 6);   // one wave per token
    int lane = threadIdx.x & 63;
    const float4* xr = (const float4*)(x + (size_t)t * DIM);
    float acc[NEXP];
#pragma unroll
    for (int e = 0; e < NEXP; ++e) acc[e] = 0.f;
#pragma unroll
    for (int i = 0; i < 4; ++i) {
        int vidx = lane + i * 64;                  // float4 index; d = vidx*4
        float4 v = xr[vidx];
        ushort4 o;
        o.x = f2bf(v.x); o.y = f2bf(v.y); o.z = f2bf(v.z); o.w = f2bf(v.w);
        ((ushort4*)xb)[(size_t)t * 256 + vidx] = o;
        const float4* wr = (const float4*)(rw + (size_t)vidx * 4 * NEXP);
        float xs[4] = {v.x, v.y, v.z, v.w};
#pragma unroll
        for (int j = 0; j < 4; ++j) {
            float4 wlo = wr[j * 2 + 0], whi = wr[j * 2 + 1];
            acc[0] += xs[j] * wlo.x; acc[1] += xs[j] * wlo.y;
            acc[2] += xs[j] * wlo.z; acc[3] += xs[j] * wlo.w;
            acc[4] += xs[j] * whi.x; acc[5] += xs[j] * whi.y;
            acc[6] += xs[j] * whi.z; acc[7] += xs[j] * whi.w;
        }
    }
#pragma unroll
    for (int e = 0; e < NEXP; ++e) {
#pragma unroll
        for (int off = 32; off; off >>= 1) acc[e] += __shfl_xor(acc[e], off);
    }
    if (lane == 0) {
        float l[NEXP];
#pragma unroll
        for (int e = 0; e < NEXP; ++e) l[e] = acc[e] + rb[e];
        float best = -1e30f; int bi = 0;
#pragma unroll
        for (int e = 0; e < NEXP; ++e) if (l[e] > best) { best = l[e]; bi = e; }
        float best2 = -1e30f; int bi2 = 0;
#pragma unroll
        for (int e = 0; e < NEXP; ++e) { if (e == bi) continue; if (l[e] > best2) { best2 = l[e]; bi2 = e; } }
        float w0 = 1.f / (1.f + expf(best2 - best));
        top_i[t * 2] = bi;  top_i[t * 2 + 1] = bi2;
        top_w[t * 2] = w0;  top_w[t * 2 + 1] = 1.f - w0;
        atomicAdd(&counts[bi], 1);
        atomicAdd(&counts[bi2], 1);
    }
}

// tile_start[e] = cumsum of ceil(counts[e]/128); tile_start[8] = total M-tiles
__global__ void scan_kernel(const int* __restrict__ counts, int* __restrict__ offsets,
                            int* __restrict__ tile_start) {
    if (threadIdx.x == 0) {
        int o = 0, t = 0;
        for (int e = 0; e < NEXP; ++e) {
            offsets[e] = o;
            tile_start[e] = t;
            t += (counts[e] + 127) >> 7;
            o += counts[e];
        }
        tile_start[NEXP] = t;
    }
}

__global__ __launch_bounds__(256) void assign_kernel(
    const int* __restrict__ top_i, const float* __restrict__ top_w,
    const int* __restrict__ offsets, int* __restrict__ cursors,
    int* __restrict__ row_token, float* __restrict__ row_w,
    int* __restrict__ slot_of) {
    int t = blockIdx.x * 256 + threadIdx.x;
    if (t >= T_TOK) return;
#pragma unroll
    for (int k = 0; k < 2; ++k) {
        int e = top_i[t * 2 + k];
        int s = atomicAdd(&cursors[e], 1);
        int g = offsets[e] + s;
        row_token[g] = t;
        row_w[g] = top_w[t * 2 + k];
        slot_of[t * 2 + k] = g;
    }
}

// ---------------- grouped GEMMs ----------------
// 128x128 tile, 4 waves, BK=32, SINGLE-buffer 16KB LDS -> 8 blocks/CU (wave ceiling).
// TLP-maximal: each block's vmcnt-drain overlaps 7 other blocks' compute (m114 at depth 8).
// chunk-XOR swizzle: LDS slot (r,c) holds global chunk c^(r&3); read c=(lane>>4)^(lane&3).

// GEMM1: h[slot][n] = relu( sum_k xb[token][k] * w1t[e][n][k] + b1[e][n] )
__global__ __launch_bounds__(256, 8) void gemm1_kernel(
    const unsigned short* __restrict__ xb,    // [T][DIM] bf16
    const unsigned short* __restrict__ w1t,   // [E][HID][DIM] bf16
    const float* __restrict__ b1,             // [E][HID]
    const int* __restrict__ row_token, const int* __restrict__ offsets,
    const int* __restrict__ counts, const int* __restrict__ ts,
    unsigned short* __restrict__ h_ws) {      // [NSLOT][HID] bf16
    const int bid = blockIdx.x;
    const int xcd = bid & 7, s = bid >> 3;    // s in [0, 4*MAXMT)
    if (s >= 4 * ts[NEXP]) return;
    int e = 0;
#pragma unroll
    for (int k = 1; k < NEXP; ++k) if (s >= 4 * ts[k]) e = k;
    const int ntile = ts[e + 1] - ts[e];
    const int local = s - 4 * ts[e];
    const int q = local / ntile;              // 0..3
    const int mt = local - q * ntile;
    const int nt = q * 8 + xcd;               // 0..31
    const int cnt = counts[e];
    const int goff = offsets[e];

    __shared__ __align__(16) unsigned short As[128][32];   // 8 KB
    __shared__ __align__(16) unsigned short Bs[128][32];   // 8 KB

    const int tid = threadIdx.x, wid = tid >> 6, lane = tid & 63;
    const int wm = wid >> 1, wn = wid & 1;

    f32x4 acc[4][4];
#pragma unroll
    for (int i = 0; i < 4; ++i)
#pragma unroll
        for (int j = 0; j < 4; ++j) acc[i][j] = (f32x4){0.f, 0.f, 0.f, 0.f};

    const unsigned short* srcA[2];
    const unsigned short* srcB[2];
#pragma unroll
    for (int it = 0; it < 2; ++it) {
        int idx = it * 256 + tid;              // 512 chunk-slots of 16B = 8KB tile
        int r = idx >> 2, kg = idx & 3;
        int sk = kg ^ (r & 3);                 // swizzled source chunk
        int rr = mt * 128 + r;
        int tok = row_token[goff + (rr < cnt ? rr : 0)];
        srcA[it] = xb + (size_t)tok * DIM + sk * 8;
        srcB[it] = w1t + ((size_t)e * HID + nt * 128 + r) * DIM + sk * 8;
    }

    for (int t = 0; t < DIM / 32; ++t) {
        const int k0 = t * 32;
#pragma unroll
        for (int it = 0; it < 2; ++it) {
            __builtin_amdgcn_global_load_lds(AS1(srcA[it] + k0),
                AS3((char*)As + (it * 4 + wid) * 1024), 16, 0, 0);
            __builtin_amdgcn_global_load_lds(AS1(srcB[it] + k0),
                AS3((char*)Bs + (it * 4 + wid) * 1024), 16, 0, 0);
        }
        __syncthreads();                       // drains vmcnt: tile ready
        {
            bf16x8 a[4], b[4];
            int ch = (lane >> 4) ^ (lane & 3);
#pragma unroll
            for (int i = 0; i < 4; ++i) {
                int row = wm * 64 + i * 16 + (lane & 15);
                a[i] = *(const bf16x8*)((const char*)As + row * 64 + ch * 16);
            }
#pragma unroll
            for (int i = 0; i < 4; ++i) {
                int row = wn * 64 + i * 16 + (lane & 15);
                b[i] = *(const bf16x8*)((const char*)Bs + row * 64 + ch * 16);
            }
#pragma unroll
            for (int i = 0; i < 4; ++i)
#pragma unroll
                for (int j = 0; j < 4; ++j)
                    acc[i][j] = mfma16(a[i], b[j], acc[i][j]);
        }
        __syncthreads();                       // all waves done reading before restage
    }

    if (mt * 128 + 128 <= cnt) {               // fast path: full tile, no bounds checks
#pragma unroll
        for (int j = 0; j < 4; ++j) {
            int n = nt * 128 + wn * 64 + j * 16 + (lane & 15);
            float bias = b1[e * HID + n];
#pragma unroll
            for (int i = 0; i < 4; ++i) {
#pragma unroll
                for (int q2 = 0; q2 < 4; ++q2) {
                    int rr = mt * 128 + wm * 64 + i * 16 + (lane >> 4) * 4 + q2;
                    float v = fmaxf(acc[i][j][q2] + bias, 0.f);
                    h_ws[(size_t)(goff + rr) * HID + n] = f2bf(v);
                }
            }
        }
    } else {
#pragma unroll
        for (int j = 0; j < 4; ++j) {
            int n = nt * 128 + wn * 64 + j * 16 + (lane & 15);
            float bias = b1[e * HID + n];
#pragma unroll
            for (int i = 0; i < 4; ++i) {
#pragma unroll
                for (int q2 = 0; q2 < 4; ++q2) {
                    int rr = mt * 128 + wm * 64 + i * 16 + (lane >> 4) * 4 + q2;
                    if (rr < cnt) {
                        float v = fmaxf(acc[i][j][q2] + bias, 0.f);
                        h_ws[(size_t)(goff + rr) * HID + n] = f2bf(v);
                    }
                }
            }
        }
    }
}

// GEMM2 (split-K): y_part[ks][slot][n] = sum_{k in slice} h[slot][k] * w2t[e][n][k]
__global__ __launch_bounds__(256, 8) void gemm2_kernel(
    const unsigned short* __restrict__ h_ws,  // [NSLOT][HID] bf16
    const unsigned short* __restrict__ w2t,   // [E][DIM][HID] bf16
    const int* __restrict__ offsets, const int* __restrict__ counts,
    const int* __restrict__ ts,
    float* __restrict__ y_part) {             // [KSPLIT][NSLOT][DIM] f32
    const int bid = blockIdx.x;
    const int xcd = bid & 7, s = bid >> 3;    // s in [0, 2*MAXMT)
    if (s >= 2 * ts[NEXP]) return;
    int e = 0;
#pragma unroll
    for (int k = 1; k < NEXP; ++k) if (s >= 2 * ts[k]) e = k;
    const int ntile = ts[e + 1] - ts[e];
    const int local = s - 2 * ts[e];
    const int ks = local / ntile;             // 0..1
    const int mt = local - ks * ntile;
    const int nt = xcd;                       // 0..7
    const int cnt = counts[e];
    const int goff = offsets[e];

    __shared__ __align__(16) unsigned short As[128][32];
    __shared__ __align__(16) unsigned short Bs[128][32];

    const int tid = threadIdx.x, wid = tid >> 6, lane = tid & 63;
    const int wm = wid >> 1, wn = wid & 1;

    f32x4 acc[4][4];
#pragma unroll
    for (int i = 0; i < 4; ++i)
#pragma unroll
        for (int j = 0; j < 4; ++j) acc[i][j] = (f32x4){0.f, 0.f, 0.f, 0.f};

    const unsigned short* srcA[2];
    const unsigned short* srcB[2];
#pragma unroll
    for (int it = 0; it < 2; ++it) {
        int idx = it * 256 + tid;
        int r = idx >> 2, kg = idx & 3;
        int sk = kg ^ (r & 3);
        int rr = mt * 128 + r;
        int g = goff + (rr < cnt ? rr : 0);
        srcA[it] = h_ws + (size_t)g * HID + sk * 8;
        srcB[it] = w2t + ((size_t)e * DIM + nt * 128 + r) * HID + sk * 8;
    }

    const int kbase = ks * KS_LEN;
    for (int t = 0; t < KS_LEN / 32; ++t) {
        const int k0 = kbase + t * 32;
#pragma unroll
        for (int it = 0; it < 2; ++it) {
            __builtin_amdgcn_global_load_lds(AS1(srcA[it] + k0),
                AS3((char*)As + (it * 4 + wid) * 1024), 16, 0, 0);
            __builtin_amdgcn_global_load_lds(AS1(srcB[it] + k0),
                AS3((char*)Bs + (it * 4 + wid) * 1024), 16, 0, 0);
        }
        __syncthreads();
        {
            bf16x8 a[4], b[4];
            int ch = (lane >> 4) ^ (lane & 3);
#pragma unroll
            for (int i = 0; i < 4; ++i) {
                int row = wm * 64 + i * 16 + (lane & 15);
                a[i] = *(const bf16x8*)((const char*)As + row * 64 + ch * 16);
            }
#pragma unroll
            for (int i = 0; i < 4; ++i) {
                int row = wn * 64 + i * 16 + (lane & 15);
                b[i] = *(const bf16x8*)((const char*)Bs + row * 64 + ch * 16);
            }
#pragma unroll
            for (int i = 0; i < 4; ++i)
#pragma unroll
                for (int j = 0; j < 4; ++j)
                    acc[i][j] = mfma16(a[i], b[j], acc[i][j]);
        }
        __syncthreads();
    }

    if (mt * 128 + 128 <= cnt) {               // fast path
#pragma unroll
        for (int j = 0; j < 4; ++j) {
            int n = nt * 128 + wn * 64 + j * 16 + (lane & 15);
#pragma unroll
            for (int i = 0; i < 4; ++i) {
#pragma unroll
                for (int q2 = 0; q2 < 4; ++q2) {
                    int rr = mt * 128 + wm * 64 + i * 16 + (lane >> 4) * 4 + q2;
                    y_part[((size_t)ks * NSLOT + goff + rr) * DIM + n] = acc[i][j][q2];
                }
            }
        }
    } else {
#pragma unroll
        for (int j = 0; j < 4; ++j) {
            int n = nt * 128 + wn * 64 + j * 16 + (lane & 15);
#pragma unroll
            for (int i = 0; i < 4; ++i) {
#pragma unroll
                for (int q2 = 0; q2 < 4; ++q2) {
                    int rr = mt * 128 + wm * 64 + i * 16 + (lane >> 4) * 4 + q2;
                    if (rr < cnt) {
                        y_part[((size_t)ks * NSLOT + goff + rr) * DIM + n] = acc[i][j][q2];
                    }
                }
            }
        }
    }
}

// out[t][d] = w0*(p0[s0]+p1[s0]+b2[e0]) + w1*(p0[s1]+p1[s1]+b2[e1])
__global__ __launch_bounds__(256) void combine_kernel(
    const float* __restrict__ y_part, const int* __restrict__ slot_of,
    const int* __restrict__ top_i, const float* __restrict__ top_w,
    const float* __restrict__ b2, float* __restrict__ out) {
    int i = blockIdx.x * 256 + threadIdx.x;    // over T*256 float4s
    int t = i >> 8, c = i & 255;
    int s0 = slot_of[t * 2], s1 = slot_of[t * 2 + 1];
    int e0 = top_i[t * 2],  e1 = top_i[t * 2 + 1];
    float w0 = top_w[t * 2], w1 = top_w[t * 2 + 1];
    const float4* P = (const float4*)y_part;
    float4 p00 = P[(size_t)s0 * 256 + c];
    float4 p01 = P[((size_t)NSLOT + s0) * 256 + c];
    float4 p10 = P[(size_t)s1 * 256 + c];
    float4 p11 = P[((size_t)NSLOT + s1) * 256 + c];
    float4 b0 = ((const float4*)b2)[e0 * 256 + c];
    float4 b1 = ((const float4*)b2)[e1 * 256 + c];
    float4 o;
    o.x = w0 * (p00.x + p01.x + b0.x) + w1 * (p10.x + p11.x + b1.x);
    o.y = w0 * (p00.y + p01.y + b0.y) + w1 * (p10.y + p11.y + b1.y);
    o.z = w0 * (p00.z + p01.z + b0.z) + w1 * (p10.z + p11.z + b1.z);
    o.w = w0 * (p00.w + p01.w + b0.w) + w1 * (p10.w + p11.w + b1.w);
    ((float4*)out)[i] = o;
}

// ---------------- launch ----------------

extern "C" void kernel_launch(void* const* d_in, const int* in_sizes, int n_in,
                              void* d_out, int out_size, void* d_ws, size_t ws_size,
                              hipStream_t stream) {
    const float* x   = (const float*)d_in[0];
    const float* rw  = (const float*)d_in[1];
    const float* rb  = (const float*)d_in[2];
    const float* w1  = (const float*)d_in[3];
    const float* b1  = (const float*)d_in[4];
    const float* w2  = (const float*)d_in[5];
    const float* b2  = (const float*)d_in[6];
    float* out = (float*)d_out;

    char* ws = (char*)d_ws;
    size_t off = 0;
    auto alloc = [&](size_t bytes) { size_t r = off; off = (off + bytes + 255) & ~(size_t)255; return r; };
    unsigned short* xb   = (unsigned short*)(ws + alloc((size_t)T_TOK * DIM * 2));
    unsigned short* w1t  = (unsigned short*)(ws + alloc((size_t)NEXP * DIM * HID * 2));  // 64 MB
    unsigned short* w2t  = (unsigned short*)(ws + alloc((size_t)NEXP * HID * DIM * 2));  // 64 MB
    unsigned short* h_ws = (unsigned short*)(ws + alloc((size_t)NSLOT * HID * 2));       // 64 MB
    int*   top_i         = (int*)(ws + alloc((size_t)NSLOT * 4));
    float* top_w         = (float*)(ws + alloc((size_t)NSLOT * 4));
    int*   slot_of       = (int*)(ws + alloc((size_t)NSLOT * 4));
    int*   row_token     = (int*)(ws + alloc((size_t)NSLOT * 4));
    float* row_w         = (float*)(ws + alloc((size_t)NSLOT * 4));
    char*  ctrl          = ws + alloc(256);
    int* counts     = (int*)(ctrl);
    int* cursors    = (int*)(ctrl + 64);
    int* offsets    = (int*)(ctrl + 128);
    int* tile_start = (int*)(ctrl + 192);      // 9 ints
    // y_part (2 x NSLOT x DIM f32 = 64 MB) aliases w1t: w1t is dead once gemm1 completes,
    // and gemm2/combine run strictly after gemm1 on the same stream.
    float* y_part = (float*)w1t;

    hipMemsetAsync(ctrl, 0, 256, stream);

    // w1 [E][DIM][HID] -> w1t [E][HID][DIM]
    transpose_conv_kernel<<<dim3(HID / 64, DIM / 64, NEXP), 256, 0, stream>>>(w1, w1t, DIM, HID);
    // w2 [E][HID][DIM] -> w2t [E][DIM][HID]
    transpose_conv_kernel<<<dim3(DIM / 64, HID / 64, NEXP), 256, 0, stream>>>(w2, w2t, HID, DIM);

    router_kernel<<<T_TOK / 4, 256, 0, stream>>>(x, rw, rb, xb, top_i, top_w, counts);
    scan_kernel<<<1, 64, 0, stream>>>(counts, offsets, tile_start);
    assign_kernel<<<T_TOK / 256, 256, 0, stream>>>(top_i, top_w, offsets, cursors,
                                                   row_token, row_w, slot_of);

    gemm1_kernel<<<GRID1, 256, 0, stream>>>(xb, w1t, b1, row_token, offsets, counts,
                                            tile_start, h_ws);
    gemm2_kernel<<<GRID2, 256, 0, stream>>>(h_ws, w2t, offsets, counts, tile_start, y_part);

    combine_kernel<<<T_TOK * 256 / 256, 256, 0, stream>>>(y_part, slot_of, top_i, top_w, b2, out);
}

// Round 10
// 1881.570 us; speedup vs baseline: 1.1910x; 1.1910x over previous
//
#include <hip/hip_runtime.h>
#include <hip/hip_bf16.h>
#include <stdint.h>

#define T_TOK 4096
#define DIM   1024
#define HID   4096
#define NEXP  8
#define NSLOT (T_TOK * 2)
#define KSPLIT 2
#define KS_LEN (HID / KSPLIT)
#define MAXMT 72                 // max sum of ceil(cnt_e/128) = 8192/128 + 8
#define GRID1 (8 * 2 * MAXMT)    // 1152: per XCD, 2 nt-groups x MAXMT mtiles (BN=256)
#define GRID2 (8 * MAXMT)        // 576:  per XCD, 1 (nt,ks)-combo x MAXMT mtiles

typedef __attribute__((ext_vector_type(8))) short bf16x8;
typedef __attribute__((ext_vector_type(4))) float f32x4;

#define AS1(p) ((const __attribute__((address_space(1))) void*)(p))
#define AS3(p) ((__attribute__((address_space(3))) void*)(p))

static __device__ __forceinline__ unsigned short f2bf(float f) {
    unsigned int u = __float_as_uint(f);
    unsigned int r = (u + 0x7fffu + ((u >> 16) & 1u)) >> 16;
    return (unsigned short)r;
}

static __device__ __forceinline__ f32x4 mfma16(bf16x8 a, bf16x8 b, f32x4 c) {
    return __builtin_amdgcn_mfma_f32_16x16x32_bf16(a, b, c, 0, 0, 0);
}

// ---------------- transpose+convert: src [E][R][C] fp32 -> dst [E][C][R] bf16 ----------------

__global__ __launch_bounds__(256) void transpose_conv_kernel(
    const float* __restrict__ src, unsigned short* __restrict__ dst, int R, int C) {
    __shared__ float tile[64][65];
    int e  = blockIdx.z;
    int r0 = blockIdx.y << 6, c0 = blockIdx.x << 6;
    int tx = threadIdx.x & 15;          // 16 lanes x float4 = 64 cols
    int ty = threadIdx.x >> 4;          // 16 rows per pass
    const float* s = src + (size_t)e * R * C;
    unsigned short* d = dst + (size_t)e * C * R;
#pragma unroll
    for (int q = 0; q < 4; ++q) {
        int r = ty + q * 16;
        float4 v = *(const float4*)(s + (size_t)(r0 + r) * C + c0 + tx * 4);
        tile[r][tx * 4 + 0] = v.x; tile[r][tx * 4 + 1] = v.y;
        tile[r][tx * 4 + 2] = v.z; tile[r][tx * 4 + 3] = v.w;
    }
    __syncthreads();
#pragma unroll
    for (int q = 0; q < 4; ++q) {
        int c = ty + q * 16;            // tile-local col; output row = c0 + c
        ushort4 o;
        o.x = f2bf(tile[tx * 4 + 0][c]);
        o.y = f2bf(tile[tx * 4 + 1][c]);
        o.z = f2bf(tile[tx * 4 + 2][c]);
        o.w = f2bf(tile[tx * 4 + 3][c]);
        *(ushort4*)(d + (size_t)(c0 + c) * R + r0 + tx * 4) = o;
    }
}

// ---------------- routing (fused x->bf16 conversion) ----------------

__global__ __launch_bounds__(256) void router_kernel(
    const float* __restrict__ x, const float* __restrict__ rw,
    const float* __restrict__ rb, unsigned short* __restrict__ xb,
    int* __restrict__ top_i, float* __restrict__ top_w, int* __restrict__ counts) {
    int t = blockIdx.x * 4 + (threadIdx.x >> 6);   // one wave per token
    int lane = threadIdx.x & 63;
    const float4* xr = (const float4*)(x + (size_t)t * DIM);
    float acc[NEXP];
#pragma unroll
    for (int e = 0; e < NEXP; ++e) acc[e] = 0.f;
#pragma unroll
    for (int i = 0; i < 4; ++i) {
        int vidx = lane + i * 64;                  // float4 index; d = vidx*4
        float4 v = xr[vidx];
        ushort4 o;
        o.x = f2bf(v.x); o.y = f2bf(v.y); o.z = f2bf(v.z); o.w = f2bf(v.w);
        ((ushort4*)xb)[(size_t)t * 256 + vidx] = o;
        const float4* wr = (const float4*)(rw + (size_t)vidx * 4 * NEXP);
        float xs[4] = {v.x, v.y, v.z, v.w};
#pragma unroll
        for (int j = 0; j < 4; ++j) {
            float4 wlo = wr[j * 2 + 0], whi = wr[j * 2 + 1];
            acc[0] += xs[j] * wlo.x; acc[1] += xs[j] * wlo.y;
            acc[2] += xs[j] * wlo.z; acc[3] += xs[j] * wlo.w;
            acc[4] += xs[j] * whi.x; acc[5] += xs[j] * whi.y;
            acc[6] += xs[j] * whi.z; acc[7] += xs[j] * whi.w;
        }
    }
#pragma unroll
    for (int e = 0; e < NEXP; ++e) {
#pragma unroll
        for (int off = 32; off; off >>= 1) acc[e] += __shfl_xor(acc[e], off);
    }
    if (lane == 0) {
        float l[NEXP];
#pragma unroll
        for (int e = 0; e < NEXP; ++e) l[e] = acc[e] + rb[e];
        float best = -1e30f; int bi = 0;
#pragma unroll
        for (int e = 0; e < NEXP; ++e) if (l[e] > best) { best = l[e]; bi = e; }
        float best2 = -1e30f; int bi2 = 0;
#pragma unroll
        for (int e = 0; e < NEXP; ++e) { if (e == bi) continue; if (l[e] > best2) { best2 = l[e]; bi2 = e; } }
        float w0 = 1.f / (1.f + expf(best2 - best));
        top_i[t * 2] = bi;  top_i[t * 2 + 1] = bi2;
        top_w[t * 2] = w0;  top_w[t * 2 + 1] = 1.f - w0;
        atomicAdd(&counts[bi], 1);
        atomicAdd(&counts[bi2], 1);
    }
}

// tile_start[e] = cumsum of ceil(counts[e]/128); tile_start[8] = total M-tiles
__global__ void scan_kernel(const int* __restrict__ counts, int* __restrict__ offsets,
                            int* __restrict__ tile_start) {
    if (threadIdx.x == 0) {
        int o = 0, t = 0;
        for (int e = 0; e < NEXP; ++e) {
            offsets[e] = o;
            tile_start[e] = t;
            t += (counts[e] + 127) >> 7;
            o += counts[e];
        }
        tile_start[NEXP] = t;
    }
}

__global__ __launch_bounds__(256) void assign_kernel(
    const int* __restrict__ top_i, const float* __restrict__ top_w,
    const int* __restrict__ offsets, int* __restrict__ cursors,
    int* __restrict__ row_token, float* __restrict__ row_w,
    int* __restrict__ slot_of) {
    int t = blockIdx.x * 256 + threadIdx.x;
    if (t >= T_TOK) return;
#pragma unroll
    for (int k = 0; k < 2; ++k) {
        int e = top_i[t * 2 + k];
        int s = atomicAdd(&cursors[e], 1);
        int g = offsets[e] + s;
        row_token[g] = t;
        row_w[g] = top_w[t * 2 + k];
        slot_of[t * 2 + k] = g;
    }
}

// ---------------- grouped GEMMs ----------------
// 128x256 tile, 8 waves (2M x 4N), BK=64, SINGLE-buffer 48KB LDS -> 3 blocks/CU.
// Verified round-8 mechanics (2-barrier K-step, 8-chunk XOR swizzle = 0 conflicts),
// 25% less staging traffic per FLOP than 128x128. acc[4][4]=64 VGPR; (512,6) caps
// at 85 VGPR (6 waves/SIMD x 60 used <= 512: residency precondition VERIFIED).

// GEMM1: h[slot][n] = relu( sum_k xb[token][k] * w1t[e][n][k] + b1[e][n] )
__global__ __launch_bounds__(512, 6) void gemm1_kernel(
    const unsigned short* __restrict__ xb,    // [T][DIM] bf16
    const unsigned short* __restrict__ w1t,   // [E][HID][DIM] bf16
    const float* __restrict__ b1,             // [E][HID]
    const int* __restrict__ row_token, const int* __restrict__ offsets,
    const int* __restrict__ counts, const int* __restrict__ ts,
    unsigned short* __restrict__ h_ws) {      // [NSLOT][HID] bf16
    const int bid = blockIdx.x;
    const int xcd = bid & 7, s = bid >> 3;    // s in [0, 2*MAXMT)
    if (s >= 2 * ts[NEXP]) return;
    int e = 0;
#pragma unroll
    for (int k = 1; k < NEXP; ++k) if (s >= 2 * ts[k]) e = k;
    const int ntile = ts[e + 1] - ts[e];
    const int local = s - 2 * ts[e];
    const int q = local / ntile;              // 0..1
    const int mt = local - q * ntile;
    const int nt = q * 8 + xcd;               // 0..15 (HID/256)
    const int cnt = counts[e];
    const int goff = offsets[e];

    __shared__ __align__(16) unsigned short As[128][64];   // 16 KB
    __shared__ __align__(16) unsigned short Bs[256][64];   // 32 KB

    const int tid = threadIdx.x, wid = tid >> 6, lane = tid & 63;
    const int wm = wid >> 2, wn = wid & 3;    // 2M x 4N wave grid

    f32x4 acc[4][4];
#pragma unroll
    for (int i = 0; i < 4; ++i)
#pragma unroll
        for (int j = 0; j < 4; ++j) acc[i][j] = (f32x4){0.f, 0.f, 0.f, 0.f};

    const unsigned short* srcA[2];
    const unsigned short* srcB[4];
#pragma unroll
    for (int it = 0; it < 2; ++it) {
        int idx = it * 512 + tid;              // 1024 chunk-slots (128 rows x 8)
        int r = idx >> 3, kg = idx & 7;
        int sk = kg ^ (r & 7);                 // swizzled source chunk
        int rr = mt * 128 + r;
        int tok = row_token[goff + (rr < cnt ? rr : 0)];
        srcA[it] = xb + (size_t)tok * DIM + sk * 8;
    }
#pragma unroll
    for (int it = 0; it < 4; ++it) {
        int idx = it * 512 + tid;              // 2048 chunk-slots (256 rows x 8)
        int r = idx >> 3, kg = idx & 7;
        int sk = kg ^ (r & 7);
        srcB[it] = w1t + ((size_t)e * HID + nt * 256 + r) * DIM + sk * 8;
    }

    for (int t = 0; t < DIM / 64; ++t) {
        const int k0 = t * 64;
#pragma unroll
        for (int it = 0; it < 2; ++it)
            __builtin_amdgcn_global_load_lds(AS1(srcA[it] + k0),
                AS3((char*)As + (it * 8 + wid) * 1024), 16, 0, 0);
#pragma unroll
        for (int it = 0; it < 4; ++it)
            __builtin_amdgcn_global_load_lds(AS1(srcB[it] + k0),
                AS3((char*)Bs + (it * 8 + wid) * 1024), 16, 0, 0);
        __syncthreads();                       // drains vmcnt: tile ready
#pragma unroll
        for (int kk = 0; kk < 2; ++kk) {
            bf16x8 a[4], b[4];
            int ch = (kk * 4 + (lane >> 4)) ^ (lane & 7);
#pragma unroll
            for (int i = 0; i < 4; ++i) {
                int row = wm * 64 + i * 16 + (lane & 15);
                a[i] = *(const bf16x8*)((const char*)As + row * 128 + ch * 16);
            }
#pragma unroll
            for (int j = 0; j < 4; ++j) {
                int row = wn * 64 + j * 16 + (lane & 15);
                b[j] = *(const bf16x8*)((const char*)Bs + row * 128 + ch * 16);
            }
#pragma unroll
            for (int i = 0; i < 4; ++i)
#pragma unroll
                for (int j = 0; j < 4; ++j)
                    acc[i][j] = mfma16(a[i], b[j], acc[i][j]);
        }
        __syncthreads();                       // all waves done reading before restage
    }

    if (mt * 128 + 128 <= cnt) {               // fast path: full tile
#pragma unroll
        for (int j = 0; j < 4; ++j) {
            int n = nt * 256 + wn * 64 + j * 16 + (lane & 15);
            float bias = b1[e * HID + n];
#pragma unroll
            for (int i = 0; i < 4; ++i) {
#pragma unroll
                for (int q2 = 0; q2 < 4; ++q2) {
                    int rr = mt * 128 + wm * 64 + i * 16 + (lane >> 4) * 4 + q2;
                    float v = fmaxf(acc[i][j][q2] + bias, 0.f);
                    h_ws[(size_t)(goff + rr) * HID + n] = f2bf(v);
                }
            }
        }
    } else {
#pragma unroll
        for (int j = 0; j < 4; ++j) {
            int n = nt * 256 + wn * 64 + j * 16 + (lane & 15);
            float bias = b1[e * HID + n];
#pragma unroll
            for (int i = 0; i < 4; ++i) {
#pragma unroll
                for (int q2 = 0; q2 < 4; ++q2) {
                    int rr = mt * 128 + wm * 64 + i * 16 + (lane >> 4) * 4 + q2;
                    if (rr < cnt) {
                        float v = fmaxf(acc[i][j][q2] + bias, 0.f);
                        h_ws[(size_t)(goff + rr) * HID + n] = f2bf(v);
                    }
                }
            }
        }
    }
}

// GEMM2 (split-K): y_part[ks][slot][n] = sum_{k in slice} h[slot][k] * w2t[e][n][k]
// XCD combo map: nt = xcd&3 (DIM/256=4), ks = xcd>>2 (KSPLIT=2).
__global__ __launch_bounds__(512, 6) void gemm2_kernel(
    const unsigned short* __restrict__ h_ws,  // [NSLOT][HID] bf16
    const unsigned short* __restrict__ w2t,   // [E][DIM][HID] bf16
    const int* __restrict__ offsets, const int* __restrict__ counts,
    const int* __restrict__ ts,
    float* __restrict__ y_part) {             // [KSPLIT][NSLOT][DIM] f32
    const int bid = blockIdx.x;
    const int xcd = bid & 7, s = bid >> 3;    // s in [0, MAXMT)
    if (s >= ts[NEXP]) return;
    int e = 0;
#pragma unroll
    for (int k = 1; k < NEXP; ++k) if (s >= ts[k]) e = k;
    const int mt = s - ts[e];
    const int nt = xcd & 3;                   // 0..3
    const int ks = xcd >> 2;                  // 0..1
    const int cnt = counts[e];
    const int goff = offsets[e];

    __shared__ __align__(16) unsigned short As[128][64];
    __shared__ __align__(16) unsigned short Bs[256][64];

    const int tid = threadIdx.x, wid = tid >> 6, lane = tid & 63;
    const int wm = wid >> 2, wn = wid & 3;

    f32x4 acc[4][4];
#pragma unroll
    for (int i = 0; i < 4; ++i)
#pragma unroll
        for (int j = 0; j < 4; ++j) acc[i][j] = (f32x4){0.f, 0.f, 0.f, 0.f};

    const unsigned short* srcA[2];
    const unsigned short* srcB[4];
#pragma unroll
    for (int it = 0; it < 2; ++it) {
        int idx = it * 512 + tid;
        int r = idx >> 3, kg = idx & 7;
        int sk = kg ^ (r & 7);
        int rr = mt * 128 + r;
        int g = goff + (rr < cnt ? rr : 0);
        srcA[it] = h_ws + (size_t)g * HID + sk * 8;
    }
#pragma unroll
    for (int it = 0; it < 4; ++it) {
        int idx = it * 512 + tid;
        int r = idx >> 3, kg = idx & 7;
        int sk = kg ^ (r & 7);
        srcB[it] = w2t + ((size_t)e * DIM + nt * 256 + r) * HID + sk * 8;
    }

    const int kbase = ks * KS_LEN;
    for (int t = 0; t < KS_LEN / 64; ++t) {
        const int k0 = kbase + t * 64;
#pragma unroll
        for (int it = 0; it < 2; ++it)
            __builtin_amdgcn_global_load_lds(AS1(srcA[it] + k0),
                AS3((char*)As + (it * 8 + wid) * 1024), 16, 0, 0);
#pragma unroll
        for (int it = 0; it < 4; ++it)
            __builtin_amdgcn_global_load_lds(AS1(srcB[it] + k0),
                AS3((char*)Bs + (it * 8 + wid) * 1024), 16, 0, 0);
        __syncthreads();
#pragma unroll
        for (int kk = 0; kk < 2; ++kk) {
            bf16x8 a[4], b[4];
            int ch = (kk * 4 + (lane >> 4)) ^ (lane & 7);
#pragma unroll
            for (int i = 0; i < 4; ++i) {
                int row = wm * 64 + i * 16 + (lane & 15);
                a[i] = *(const bf16x8*)((const char*)As + row * 128 + ch * 16);
            }
#pragma unroll
            for (int j = 0; j < 4; ++j) {
                int row = wn * 64 + j * 16 + (lane & 15);
                b[j] = *(const bf16x8*)((const char*)Bs + row * 128 + ch * 16);
            }
#pragma unroll
            for (int i = 0; i < 4; ++i)
#pragma unroll
                for (int j = 0; j < 4; ++j)
                    acc[i][j] = mfma16(a[i], b[j], acc[i][j]);
        }
        __syncthreads();
    }

    if (mt * 128 + 128 <= cnt) {               // fast path
#pragma unroll
        for (int j = 0; j < 4; ++j) {
            int n = nt * 256 + wn * 64 + j * 16 + (lane & 15);
#pragma unroll
            for (int i = 0; i < 4; ++i) {
#pragma unroll
                for (int q2 = 0; q2 < 4; ++q2) {
                    int rr = mt * 128 + wm * 64 + i * 16 + (lane >> 4) * 4 + q2;
                    y_part[((size_t)ks * NSLOT + goff + rr) * DIM + n] = acc[i][j][q2];
                }
            }
        }
    } else {
#pragma unroll
        for (int j = 0; j < 4; ++j) {
            int n = nt * 256 + wn * 64 + j * 16 + (lane & 15);
#pragma unroll
            for (int i = 0; i < 4; ++i) {
#pragma unroll
                for (int q2 = 0; q2 < 4; ++q2) {
                    int rr = mt * 128 + wm * 64 + i * 16 + (lane >> 4) * 4 + q2;
                    if (rr < cnt) {
                        y_part[((size_t)ks * NSLOT + goff + rr) * DIM + n] = acc[i][j][q2];
                    }
                }
            }
        }
    }
}

// out[t][d] = w0*(p0[s0]+p1[s0]+b2[e0]) + w1*(p0[s1]+p1[s1]+b2[e1])
__global__ __launch_bounds__(256) void combine_kernel(
    const float* __restrict__ y_part, const int* __restrict__ slot_of,
    const int* __restrict__ top_i, const float* __restrict__ top_w,
    const float* __restrict__ b2, float* __restrict__ out) {
    int i = blockIdx.x * 256 + threadIdx.x;    // over T*256 float4s
    int t = i >> 8, c = i & 255;
    int s0 = slot_of[t * 2], s1 = slot_of[t * 2 + 1];
    int e0 = top_i[t * 2],  e1 = top_i[t * 2 + 1];
    float w0 = top_w[t * 2], w1 = top_w[t * 2 + 1];
    const float4* P = (const float4*)y_part;
    float4 p00 = P[(size_t)s0 * 256 + c];
    float4 p01 = P[((size_t)NSLOT + s0) * 256 + c];
    float4 p10 = P[(size_t)s1 * 256 + c];
    float4 p11 = P[((size_t)NSLOT + s1) * 256 + c];
    float4 b0 = ((const float4*)b2)[e0 * 256 + c];
    float4 b1 = ((const float4*)b2)[e1 * 256 + c];
    float4 o;
    o.x = w0 * (p00.x + p01.x + b0.x) + w1 * (p10.x + p11.x + b1.x);
    o.y = w0 * (p00.y + p01.y + b0.y) + w1 * (p10.y + p11.y + b1.y);
    o.z = w0 * (p00.z + p01.z + b0.z) + w1 * (p10.z + p11.z + b1.z);
    o.w = w0 * (p00.w + p01.w + b0.w) + w1 * (p10.w + p11.w + b1.w);
    ((float4*)out)[i] = o;
}

// ---------------- launch ----------------

extern "C" void kernel_launch(void* const* d_in, const int* in_sizes, int n_in,
                              void* d_out, int out_size, void* d_ws, size_t ws_size,
                              hipStream_t stream) {
    const float* x   = (const float*)d_in[0];
    const float* rw  = (const float*)d_in[1];
    const float* rb  = (const float*)d_in[2];
    const float* w1  = (const float*)d_in[3];
    const float* b1  = (const float*)d_in[4];
    const float* w2  = (const float*)d_in[5];
    const float* b2  = (const float*)d_in[6];
    float* out = (float*)d_out;

    char* ws = (char*)d_ws;
    size_t off = 0;
    auto alloc = [&](size_t bytes) { size_t r = off; off = (off + bytes + 255) & ~(size_t)255; return r; };
    unsigned short* xb   = (unsigned short*)(ws + alloc((size_t)T_TOK * DIM * 2));
    unsigned short* w1t  = (unsigned short*)(ws + alloc((size_t)NEXP * DIM * HID * 2));  // 64 MB
    unsigned short* w2t  = (unsigned short*)(ws + alloc((size_t)NEXP * HID * DIM * 2));  // 64 MB
    unsigned short* h_ws = (unsigned short*)(ws + alloc((size_t)NSLOT * HID * 2));       // 64 MB
    int*   top_i         = (int*)(ws + alloc((size_t)NSLOT * 4));
    float* top_w         = (float*)(ws + alloc((size_t)NSLOT * 4));
    int*   slot_of       = (int*)(ws + alloc((size_t)NSLOT * 4));
    int*   row_token     = (int*)(ws + alloc((size_t)NSLOT * 4));
    float* row_w         = (float*)(ws + alloc((size_t)NSLOT * 4));
    char*  ctrl          = ws + alloc(256);
    int* counts     = (int*)(ctrl);
    int* cursors    = (int*)(ctrl + 64);
    int* offsets    = (int*)(ctrl + 128);
    int* tile_start = (int*)(ctrl + 192);      // 9 ints
    // y_part (2 x NSLOT x DIM f32 = 64 MB) aliases w1t: w1t is dead once gemm1 completes,
    // and gemm2/combine run strictly after gemm1 on the same stream.
    float* y_part = (float*)w1t;

    hipMemsetAsync(ctrl, 0, 256, stream);

    // w1 [E][DIM][HID] -> w1t [E][HID][DIM]
    transpose_conv_kernel<<<dim3(HID / 64, DIM / 64, NEXP), 256, 0, stream>>>(w1, w1t, DIM, HID);
    // w2 [E][HID][DIM] -> w2t [E][DIM][HID]
    transpose_conv_kernel<<<dim3(DIM / 64, HID / 64, NEXP), 256, 0, stream>>>(w2, w2t, HID, DIM);

    router_kernel<<<T_TOK / 4, 256, 0, stream>>>(x, rw, rb, xb, top_i, top_w, counts);
    scan_kernel<<<1, 64, 0, stream>>>(counts, offsets, tile_start);
    assign_kernel<<<T_TOK / 256, 256, 0, stream>>>(top_i, top_w, offsets, cursors,
                                                   row_token, row_w, slot_of);

    gemm1_kernel<<<GRID1, 512, 0, stream>>>(xb, w1t, b1, row_token, offsets, counts,
                                            tile_start, h_ws);
    gemm2_kernel<<<GRID2, 512, 0, stream>>>(h_ws, w2t, offsets, counts, tile_start, y_part);

    combine_kernel<<<T_TOK * 256 / 256, 256, 0, stream>>>(y_part, slot_of, top_i, top_w, b2, out);
}

// Round 11
// 402.794 us; speedup vs baseline: 5.5636x; 4.6713x over previous
//
#include <hip/hip_runtime.h>
#include <hip/hip_bf16.h>
#include <stdint.h>

#define T_TOK 4096
#define DIM   1024
#define HID   4096
#define NEXP  8
#define NSLOT (T_TOK * 2)
#define KSPLIT 2
#define KS_LEN (HID / KSPLIT)
#define MAXMT 72                 // max sum of ceil(cnt_e/128) = 8192/128 + 8
#define GRID1 (8 * 4 * MAXMT)    // 2304 gemm1 job slots
#define GRID2 (8 * 2 * MAXMT)    // 1152 gemm2 job slots
#define TW1_BLKS 8192            // transpose w1: (HID/64)*(DIM/64)*NEXP
#define TW2_BLKS 8192            // transpose w2: (DIM/64)*(HID/64)*NEXP

typedef __attribute__((ext_vector_type(8))) short bf16x8;
typedef __attribute__((ext_vector_type(4))) float f32x4;

#define AS1(p) ((const __attribute__((address_space(1))) void*)(p))
#define AS3(p) ((__attribute__((address_space(3))) void*)(p))

static __device__ __forceinline__ unsigned short f2bf(float f) {
    unsigned int u = __float_as_uint(f);
    unsigned int r = (u + 0x7fffu + ((u >> 16) & 1u)) >> 16;
    return (unsigned short)r;
}

static __device__ __forceinline__ f32x4 mfma16(bf16x8 a, bf16x8 b, f32x4 c) {
    return __builtin_amdgcn_mfma_f32_16x16x32_bf16(a, b, c, 0, 0, 0);
}

// transpose one 64x64 tile: src [E][R][C] fp32 -> dst [E][C][R] bf16
static __device__ __forceinline__ void transpose_tile(
    const float* __restrict__ src, unsigned short* __restrict__ dst,
    int R, int C, int e, int r0, int c0, char* smem) {
    float (*tile)[65] = (float (*)[65])smem;
    int tx = threadIdx.x & 15;          // 16 lanes x float4 = 64 cols
    int ty = threadIdx.x >> 4;          // 16 rows per pass
    const float* s = src + (size_t)e * R * C;
    unsigned short* d = dst + (size_t)e * C * R;
#pragma unroll
    for (int q = 0; q < 4; ++q) {
        int r = ty + q * 16;
        float4 v = *(const float4*)(s + (size_t)(r0 + r) * C + c0 + tx * 4);
        tile[r][tx * 4 + 0] = v.x; tile[r][tx * 4 + 1] = v.y;
        tile[r][tx * 4 + 2] = v.z; tile[r][tx * 4 + 3] = v.w;
    }
    __syncthreads();
#pragma unroll
    for (int q = 0; q < 4; ++q) {
        int c = ty + q * 16;            // tile-local col; output row = c0 + c
        ushort4 o;
        o.x = f2bf(tile[tx * 4 + 0][c]);
        o.y = f2bf(tile[tx * 4 + 1][c]);
        o.z = f2bf(tile[tx * 4 + 2][c]);
        o.w = f2bf(tile[tx * 4 + 3][c]);
        *(ushort4*)(d + (size_t)(c0 + c) * R + r0 + tx * 4) = o;
    }
}

// ---------------- fused: transpose w1 + router (independent roles, one launch) ----------------

__global__ __launch_bounds__(256) void pre_kernel(
    const float* __restrict__ w1, unsigned short* __restrict__ w1t,
    const float* __restrict__ x, const float* __restrict__ rw,
    const float* __restrict__ rb, unsigned short* __restrict__ xb,
    int* __restrict__ top_i, float* __restrict__ top_w, int* __restrict__ counts) {
    __shared__ __align__(16) char smem[16640];
    const int bid = blockIdx.x;
    if (bid < TW1_BLKS) {
        // w1 [E][DIM][HID] -> w1t [E][HID][DIM]: R=DIM, C=HID; 64 c-tiles x 16 r-tiles per e
        int e = bid >> 10;
        int rest = bid & 1023;
        int c0 = (rest & 63) << 6;
        int r0 = (rest >> 6) << 6;
        transpose_tile(w1, w1t, DIM, HID, e, r0, c0, smem);
        return;
    }
    // router: one wave per token (fused x->bf16 conversion)
    int t = (bid - TW1_BLKS) * 4 + (threadIdx.x >> 6);
    int lane = threadIdx.x & 63;
    const float4* xr = (const float4*)(x + (size_t)t * DIM);
    float acc[NEXP];
#pragma unroll
    for (int e = 0; e < NEXP; ++e) acc[e] = 0.f;
#pragma unroll
    for (int i = 0; i < 4; ++i) {
        int vidx = lane + i * 64;
        float4 v = xr[vidx];
        ushort4 o;
        o.x = f2bf(v.x); o.y = f2bf(v.y); o.z = f2bf(v.z); o.w = f2bf(v.w);
        ((ushort4*)xb)[(size_t)t * 256 + vidx] = o;
        const float4* wr = (const float4*)(rw + (size_t)vidx * 4 * NEXP);
        float xs[4] = {v.x, v.y, v.z, v.w};
#pragma unroll
        for (int j = 0; j < 4; ++j) {
            float4 wlo = wr[j * 2 + 0], whi = wr[j * 2 + 1];
            acc[0] += xs[j] * wlo.x; acc[1] += xs[j] * wlo.y;
            acc[2] += xs[j] * wlo.z; acc[3] += xs[j] * wlo.w;
            acc[4] += xs[j] * whi.x; acc[5] += xs[j] * whi.y;
            acc[6] += xs[j] * whi.z; acc[7] += xs[j] * whi.w;
        }
    }
#pragma unroll
    for (int e = 0; e < NEXP; ++e) {
#pragma unroll
        for (int off = 32; off; off >>= 1) acc[e] += __shfl_xor(acc[e], off);
    }
    if (lane == 0) {
        float l[NEXP];
#pragma unroll
        for (int e = 0; e < NEXP; ++e) l[e] = acc[e] + rb[e];
        float best = -1e30f; int bi = 0;
#pragma unroll
        for (int e = 0; e < NEXP; ++e) if (l[e] > best) { best = l[e]; bi = e; }
        float best2 = -1e30f; int bi2 = 0;
#pragma unroll
        for (int e = 0; e < NEXP; ++e) { if (e == bi) continue; if (l[e] > best2) { best2 = l[e]; bi2 = e; } }
        float w0 = 1.f / (1.f + expf(best2 - best));
        top_i[t * 2] = bi;  top_i[t * 2 + 1] = bi2;
        top_w[t * 2] = w0;  top_w[t * 2 + 1] = 1.f - w0;
        atomicAdd(&counts[bi], 1);
        atomicAdd(&counts[bi2], 1);
    }
}

// tile_start[e] = cumsum of ceil(counts[e]/128); tile_start[8] = total M-tiles
__global__ void scan_kernel(const int* __restrict__ counts, int* __restrict__ offsets,
                            int* __restrict__ tile_start) {
    if (threadIdx.x == 0) {
        int o = 0, t = 0;
        for (int e = 0; e < NEXP; ++e) {
            offsets[e] = o;
            tile_start[e] = t;
            t += (counts[e] + 127) >> 7;
            o += counts[e];
        }
        tile_start[NEXP] = t;
    }
}

__global__ __launch_bounds__(256) void assign_kernel(
    const int* __restrict__ top_i, const float* __restrict__ top_w,
    const int* __restrict__ offsets, int* __restrict__ cursors,
    int* __restrict__ row_token, float* __restrict__ row_w,
    int* __restrict__ slot_of) {
    int t = blockIdx.x * 256 + threadIdx.x;
    if (t >= T_TOK) return;
#pragma unroll
    for (int k = 0; k < 2; ++k) {
        int e = top_i[t * 2 + k];
        int s = atomicAdd(&cursors[e], 1);
        int g = offsets[e] + s;
        row_token[g] = t;
        row_w[g] = top_w[t * 2 + k];
        slot_of[t * 2 + k] = g;
    }
}

// ---------------- fused: GEMM1 + transpose w2 (round-8 verified GEMM body) ----------------
// gemm1: 128x128 tile, 4 waves, BK=64, single-buffer 32KB LDS, plain __syncthreads()
// (residency covers the drain — m114), 8-chunk XOR swizzle (conflicts=0), work-queue
// balance + XCD expert affinity. Appended blocks transpose w2 (read by gemm2 only —
// no intra-launch dependency); they fill the CUs/BW gemm1 leaves idle.

__global__ __launch_bounds__(256, 4) void g1_kernel(
    const unsigned short* __restrict__ xb,    // [T][DIM] bf16
    const unsigned short* __restrict__ w1t,   // [E][HID][DIM] bf16
    const float* __restrict__ b1,             // [E][HID]
    const int* __restrict__ row_token, const int* __restrict__ offsets,
    const int* __restrict__ counts, const int* __restrict__ ts,
    unsigned short* __restrict__ h_ws,        // [NSLOT][HID] bf16
    const float* __restrict__ w2, unsigned short* __restrict__ w2t) {
    __shared__ __align__(16) char smem[32768];
    const int bid = blockIdx.x;
    if (bid >= GRID1) {
        // w2 [E][HID][DIM] -> w2t [E][DIM][HID]: R=HID, C=DIM; 16 c-tiles x 64 r-tiles per e
        int r = bid - GRID1;
        int e = r >> 10;
        int rest = r & 1023;
        int c0 = (rest & 15) << 6;
        int r0 = (rest >> 4) << 6;
        transpose_tile(w2, w2t, HID, DIM, e, r0, c0, smem);
        return;
    }
    const int xcd = bid & 7, s = bid >> 3;    // s in [0, 4*MAXMT)
    if (s >= 4 * ts[NEXP]) return;
    int e = 0;
#pragma unroll
    for (int k = 1; k < NEXP; ++k) if (s >= 4 * ts[k]) e = k;
    const int ntile = ts[e + 1] - ts[e];
    const int local = s - 4 * ts[e];
    const int q = local / ntile;              // 0..3
    const int mt = local - q * ntile;
    const int nt = q * 8 + xcd;               // 0..31
    const int cnt = counts[e];
    const int goff = offsets[e];

    unsigned short (*As)[64] = (unsigned short (*)[64])smem;            // 16 KB
    unsigned short (*Bs)[64] = (unsigned short (*)[64])(smem + 16384);  // 16 KB

    const int tid = threadIdx.x, wid = tid >> 6, lane = tid & 63;
    const int wm = wid >> 1, wn = wid & 1;

    f32x4 acc[4][4];
#pragma unroll
    for (int i = 0; i < 4; ++i)
#pragma unroll
        for (int j = 0; j < 4; ++j) acc[i][j] = (f32x4){0.f, 0.f, 0.f, 0.f};

    const unsigned short* srcA[4];
    const unsigned short* srcB[4];
#pragma unroll
    for (int it = 0; it < 4; ++it) {
        int idx = it * 256 + tid;
        int r = idx >> 3, kg = idx & 7;
        int sk = kg ^ (r & 7);                 // swizzled source chunk
        int rr = mt * 128 + r;
        int tok = row_token[goff + (rr < cnt ? rr : 0)];
        srcA[it] = xb + (size_t)tok * DIM + sk * 8;
        srcB[it] = w1t + ((size_t)e * HID + nt * 128 + r) * DIM + sk * 8;
    }

    for (int t = 0; t < 16; ++t) {
        const int k0 = t * 64;
#pragma unroll
        for (int it = 0; it < 4; ++it) {
            __builtin_amdgcn_global_load_lds(AS1(srcA[it] + k0),
                AS3((char*)As + (it * 4 + wid) * 1024), 16, 0, 0);
            __builtin_amdgcn_global_load_lds(AS1(srcB[it] + k0),
                AS3((char*)Bs + (it * 4 + wid) * 1024), 16, 0, 0);
        }
        __syncthreads();                       // drains vmcnt: tile ready
#pragma unroll
        for (int kk = 0; kk < 2; ++kk) {
            bf16x8 a[4], b[4];
            int ch = (kk * 4 + (lane >> 4)) ^ (lane & 7);
#pragma unroll
            for (int i = 0; i < 4; ++i) {
                int row = wm * 64 + i * 16 + (lane & 15);
                a[i] = *(const bf16x8*)((const char*)As + row * 128 + ch * 16);
            }
#pragma unroll
            for (int i = 0; i < 4; ++i) {
                int row = wn * 64 + i * 16 + (lane & 15);
                b[i] = *(const bf16x8*)((const char*)Bs + row * 128 + ch * 16);
            }
#pragma unroll
            for (int i = 0; i < 4; ++i)
#pragma unroll
                for (int j = 0; j < 4; ++j)
                    acc[i][j] = mfma16(a[i], b[j], acc[i][j]);
        }
        __syncthreads();                       // all waves done reading before restage
    }

    if (mt * 128 + 128 <= cnt) {               // fast path: full tile
#pragma unroll
        for (int j = 0; j < 4; ++j) {
            int n = nt * 128 + wn * 64 + j * 16 + (lane & 15);
            float bias = b1[e * HID + n];
#pragma unroll
            for (int i = 0; i < 4; ++i) {
#pragma unroll
                for (int q2 = 0; q2 < 4; ++q2) {
                    int rr = mt * 128 + wm * 64 + i * 16 + (lane >> 4) * 4 + q2;
                    float v = fmaxf(acc[i][j][q2] + bias, 0.f);
                    h_ws[(size_t)(goff + rr) * HID + n] = f2bf(v);
                }
            }
        }
    } else {
#pragma unroll
        for (int j = 0; j < 4; ++j) {
            int n = nt * 128 + wn * 64 + j * 16 + (lane & 15);
            float bias = b1[e * HID + n];
#pragma unroll
            for (int i = 0; i < 4; ++i) {
#pragma unroll
                for (int q2 = 0; q2 < 4; ++q2) {
                    int rr = mt * 128 + wm * 64 + i * 16 + (lane >> 4) * 4 + q2;
                    if (rr < cnt) {
                        float v = fmaxf(acc[i][j][q2] + bias, 0.f);
                        h_ws[(size_t)(goff + rr) * HID + n] = f2bf(v);
                    }
                }
            }
        }
    }
}

// GEMM2 (split-K): y_part[ks][slot][n] = sum_{k in slice} h[slot][k] * w2t[e][n][k]
__global__ __launch_bounds__(256, 4) void gemm2_kernel(
    const unsigned short* __restrict__ h_ws,  // [NSLOT][HID] bf16
    const unsigned short* __restrict__ w2t,   // [E][DIM][HID] bf16
    const int* __restrict__ offsets, const int* __restrict__ counts,
    const int* __restrict__ ts,
    float* __restrict__ y_part) {             // [KSPLIT][NSLOT][DIM] f32
    const int bid = blockIdx.x;
    const int xcd = bid & 7, s = bid >> 3;    // s in [0, 2*MAXMT)
    if (s >= 2 * ts[NEXP]) return;
    int e = 0;
#pragma unroll
    for (int k = 1; k < NEXP; ++k) if (s >= 2 * ts[k]) e = k;
    const int ntile = ts[e + 1] - ts[e];
    const int local = s - 2 * ts[e];
    const int ks = local / ntile;             // 0..1
    const int mt = local - ks * ntile;
    const int nt = xcd;                       // 0..7
    const int cnt = counts[e];
    const int goff = offsets[e];

    __shared__ __align__(16) unsigned short As[128][64];
    __shared__ __align__(16) unsigned short Bs[128][64];

    const int tid = threadIdx.x, wid = tid >> 6, lane = tid & 63;
    const int wm = wid >> 1, wn = wid & 1;

    f32x4 acc[4][4];
#pragma unroll
    for (int i = 0; i < 4; ++i)
#pragma unroll
        for (int j = 0; j < 4; ++j) acc[i][j] = (f32x4){0.f, 0.f, 0.f, 0.f};

    const unsigned short* srcA[4];
    const unsigned short* srcB[4];
#pragma unroll
    for (int it = 0; it < 4; ++it) {
        int idx = it * 256 + tid;
        int r = idx >> 3, kg = idx & 7;
        int sk = kg ^ (r & 7);
        int rr = mt * 128 + r;
        int g = goff + (rr < cnt ? rr : 0);
        srcA[it] = h_ws + (size_t)g * HID + sk * 8;
        srcB[it] = w2t + ((size_t)e * DIM + nt * 128 + r) * HID + sk * 8;
    }

    const int kbase = ks * KS_LEN;
    for (int t = 0; t < KS_LEN / 64; ++t) {
        const int k0 = kbase + t * 64;
#pragma unroll
        for (int it = 0; it < 4; ++it) {
            __builtin_amdgcn_global_load_lds(AS1(srcA[it] + k0),
                AS3((char*)As + (it * 4 + wid) * 1024), 16, 0, 0);
            __builtin_amdgcn_global_load_lds(AS1(srcB[it] + k0),
                AS3((char*)Bs + (it * 4 + wid) * 1024), 16, 0, 0);
        }
        __syncthreads();
#pragma unroll
        for (int kk = 0; kk < 2; ++kk) {
            bf16x8 a[4], b[4];
            int ch = (kk * 4 + (lane >> 4)) ^ (lane & 7);
#pragma unroll
            for (int i = 0; i < 4; ++i) {
                int row = wm * 64 + i * 16 + (lane & 15);
                a[i] = *(const bf16x8*)((const char*)As + row * 128 + ch * 16);
            }
#pragma unroll
            for (int i = 0; i < 4; ++i) {
                int row = wn * 64 + i * 16 + (lane & 15);
                b[i] = *(const bf16x8*)((const char*)Bs + row * 128 + ch * 16);
            }
#pragma unroll
            for (int i = 0; i < 4; ++i)
#pragma unroll
                for (int j = 0; j < 4; ++j)
                    acc[i][j] = mfma16(a[i], b[j], acc[i][j]);
        }
        __syncthreads();
    }

    if (mt * 128 + 128 <= cnt) {               // fast path
#pragma unroll
        for (int j = 0; j < 4; ++j) {
            int n = nt * 128 + wn * 64 + j * 16 + (lane & 15);
#pragma unroll
            for (int i = 0; i < 4; ++i) {
#pragma unroll
                for (int q2 = 0; q2 < 4; ++q2) {
                    int rr = mt * 128 + wm * 64 + i * 16 + (lane >> 4) * 4 + q2;
                    y_part[((size_t)ks * NSLOT + goff + rr) * DIM + n] = acc[i][j][q2];
                }
            }
        }
    } else {
#pragma unroll
        for (int j = 0; j < 4; ++j) {
            int n = nt * 128 + wn * 64 + j * 16 + (lane & 15);
#pragma unroll
            for (int i = 0; i < 4; ++i) {
#pragma unroll
                for (int q2 = 0; q2 < 4; ++q2) {
                    int rr = mt * 128 + wm * 64 + i * 16 + (lane >> 4) * 4 + q2;
                    if (rr < cnt) {
                        y_part[((size_t)ks * NSLOT + goff + rr) * DIM + n] = acc[i][j][q2];
                    }
                }
            }
        }
    }
}

// out[t][d] = w0*(p0[s0]+p1[s0]+b2[e0]) + w1*(p0[s1]+p1[s1]+b2[e1])
__global__ __launch_bounds__(256) void combine_kernel(
    const float* __restrict__ y_part, const int* __restrict__ slot_of,
    const int* __restrict__ top_i, const float* __restrict__ top_w,
    const float* __restrict__ b2, float* __restrict__ out) {
    int i = blockIdx.x * 256 + threadIdx.x;    // over T*256 float4s
    int t = i >> 8, c = i & 255;
    int s0 = slot_of[t * 2], s1 = slot_of[t * 2 + 1];
    int e0 = top_i[t * 2],  e1 = top_i[t * 2 + 1];
    float w0 = top_w[t * 2], w1 = top_w[t * 2 + 1];
    const float4* P = (const float4*)y_part;
    float4 p00 = P[(size_t)s0 * 256 + c];
    float4 p01 = P[((size_t)NSLOT + s0) * 256 + c];
    float4 p10 = P[(size_t)s1 * 256 + c];
    float4 p11 = P[((size_t)NSLOT + s1) * 256 + c];
    float4 b0 = ((const float4*)b2)[e0 * 256 + c];
    float4 b1 = ((const float4*)b2)[e1 * 256 + c];
    float4 o;
    o.x = w0 * (p00.x + p01.x + b0.x) + w1 * (p10.x + p11.x + b1.x);
    o.y = w0 * (p00.y + p01.y + b0.y) + w1 * (p10.y + p11.y + b1.y);
    o.z = w0 * (p00.z + p01.z + b0.z) + w1 * (p10.z + p11.z + b1.z);
    o.w = w0 * (p00.w + p01.w + b0.w) + w1 * (p10.w + p11.w + b1.w);
    ((float4*)out)[i] = o;
}

// ---------------- launch ----------------

extern "C" void kernel_launch(void* const* d_in, const int* in_sizes, int n_in,
                              void* d_out, int out_size, void* d_ws, size_t ws_size,
                              hipStream_t stream) {
    const float* x   = (const float*)d_in[0];
    const float* rw  = (const float*)d_in[1];
    const float* rb  = (const float*)d_in[2];
    const float* w1  = (const float*)d_in[3];
    const float* b1  = (const float*)d_in[4];
    const float* w2  = (const float*)d_in[5];
    const float* b2  = (const float*)d_in[6];
    float* out = (float*)d_out;

    char* ws = (char*)d_ws;
    size_t off = 0;
    auto alloc = [&](size_t bytes) { size_t r = off; off = (off + bytes + 255) & ~(size_t)255; return r; };
    unsigned short* xb   = (unsigned short*)(ws + alloc((size_t)T_TOK * DIM * 2));
    unsigned short* w1t  = (unsigned short*)(ws + alloc((size_t)NEXP * DIM * HID * 2));  // 64 MB
    unsigned short* w2t  = (unsigned short*)(ws + alloc((size_t)NEXP * HID * DIM * 2));  // 64 MB
    unsigned short* h_ws = (unsigned short*)(ws + alloc((size_t)NSLOT * HID * 2));       // 64 MB
    int*   top_i         = (int*)(ws + alloc((size_t)NSLOT * 4));
    float* top_w         = (float*)(ws + alloc((size_t)NSLOT * 4));
    int*   slot_of       = (int*)(ws + alloc((size_t)NSLOT * 4));
    int*   row_token     = (int*)(ws + alloc((size_t)NSLOT * 4));
    float* row_w         = (float*)(ws + alloc((size_t)NSLOT * 4));
    char*  ctrl          = ws + alloc(256);
    int* counts     = (int*)(ctrl);
    int* cursors    = (int*)(ctrl + 64);
    int* offsets    = (int*)(ctrl + 128);
    int* tile_start = (int*)(ctrl + 192);      // 9 ints
    // y_part (2 x NSLOT x DIM f32 = 64 MB) aliases w1t: w1t is dead once g1 completes,
    // and gemm2/combine run strictly after g1 on the same stream.
    float* y_part = (float*)w1t;

    hipMemsetAsync(ctrl, 0, 256, stream);

    // fused: transpose w1 + router
    pre_kernel<<<TW1_BLKS + T_TOK / 4, 256, 0, stream>>>(w1, w1t, x, rw, rb, xb,
                                                         top_i, top_w, counts);
    scan_kernel<<<1, 64, 0, stream>>>(counts, offsets, tile_start);
    assign_kernel<<<T_TOK / 256, 256, 0, stream>>>(top_i, top_w, offsets, cursors,
                                                   row_token, row_w, slot_of);

    // fused: gemm1 + transpose w2 (w2t consumed only by gemm2, next launch)
    g1_kernel<<<GRID1 + TW2_BLKS, 256, 0, stream>>>(xb, w1t, b1, row_token, offsets,
                                                    counts, tile_start, h_ws, w2, w2t);
    gemm2_kernel<<<GRID2, 256, 0, stream>>>(h_ws, w2t, offsets, counts, tile_start, y_part);

    combine_kernel<<<T_TOK * 256 / 256, 256, 0, stream>>>(y_part, slot_of, top_i, top_w, b2, out);
}

// Round 12
// 401.615 us; speedup vs baseline: 5.5799x; 1.0029x over previous
//
#include <hip/hip_runtime.h>
#include <hip/hip_bf16.h>
#include <stdint.h>

#define T_TOK 4096
#define DIM   1024
#define HID   4096
#define NEXP  8
#define NSLOT (T_TOK * 2)
#define KSPLIT 2
#define KS_LEN (HID / KSPLIT)
#define MAXMT 72                 // max sum of ceil(cnt_e/128) = 8192/128 + 8
#define GRID1 (8 * 4 * MAXMT)    // 2304 gemm1 job slots
#define GRID2 (8 * 2 * MAXMT)    // 1152 gemm2 job slots
#define TW1_BLKS 4096            // transpose w1: (DIM/128)*(HID/64)*NEXP = 8*64*8
#define TW2_BLKS 4096            // transpose w2: (HID/128)*(DIM/64)*NEXP = 32*16*8

typedef __attribute__((ext_vector_type(8))) short bf16x8;
typedef __attribute__((ext_vector_type(4))) float f32x4;

#define AS1(p) ((const __attribute__((address_space(1))) void*)(p))
#define AS3(p) ((__attribute__((address_space(3))) void*)(p))

static __device__ __forceinline__ unsigned short f2bf(float f) {
    unsigned int u = __float_as_uint(f);
    unsigned int r = (u + 0x7fffu + ((u >> 16) & 1u)) >> 16;
    return (unsigned short)r;
}

static __device__ __forceinline__ f32x4 mfma16(bf16x8 a, bf16x8 b, f32x4 c) {
    return __builtin_amdgcn_mfma_f32_16x16x32_bf16(a, b, c, 0, 0, 0);
}

// transpose one 128(src rows) x 64(src cols) tile: src [E][R][C] fp32 -> dst [E][C][R] bf16.
// 8 x 16B loads/thread in flight; 256-B contiguous write segments per output row.
static __device__ __forceinline__ void transpose_tile128(
    const float* __restrict__ src, unsigned short* __restrict__ dst,
    int R, int C, int e, int r0, int c0, char* smem) {
    float (*tile)[65] = (float (*)[65])smem;   // [128][65] fp32 = 33280 B
    const int tid = threadIdx.x;
    const float* s = src + (size_t)e * R * C;
    unsigned short* d = dst + (size_t)e * C * R;
#pragma unroll
    for (int t = 0; t < 8; ++t) {
        int idx = t * 256 + tid;               // 2048 float4 slots: 128 rows x 16
        int row = idx >> 4, cq = idx & 15;
        float4 v = *(const float4*)(s + (size_t)(r0 + row) * C + c0 + cq * 4);
        tile[row][cq * 4 + 0] = v.x; tile[row][cq * 4 + 1] = v.y;
        tile[row][cq * 4 + 2] = v.z; tile[row][cq * 4 + 3] = v.w;
    }
    __syncthreads();
#pragma unroll
    for (int t = 0; t < 8; ++t) {
        int idx = t * 256 + tid;               // 2048 ushort4 slots: 64 out-rows x 32
        int c = idx >> 5, tx = idx & 31;
        ushort4 o;
        o.x = f2bf(tile[tx * 4 + 0][c]);
        o.y = f2bf(tile[tx * 4 + 1][c]);
        o.z = f2bf(tile[tx * 4 + 2][c]);
        o.w = f2bf(tile[tx * 4 + 3][c]);
        *(ushort4*)(d + (size_t)(c0 + c) * R + r0 + tx * 4) = o;
    }
}

// ---------------- fused: transpose w1 + router (independent roles, one launch) ----------------

__global__ __launch_bounds__(256) void pre_kernel(
    const float* __restrict__ w1, unsigned short* __restrict__ w1t,
    const float* __restrict__ x, const float* __restrict__ rw,
    const float* __restrict__ rb, unsigned short* __restrict__ xb,
    int* __restrict__ top_i, float* __restrict__ top_w, int* __restrict__ counts) {
    __shared__ __align__(16) char smem[33280];
    const int bid = blockIdx.x;
    if (bid < TW1_BLKS) {
        // w1 [E][DIM][HID] -> w1t [E][HID][DIM]: R=DIM(8 r-tiles of 128), C=HID(64 c-tiles)
        int e = bid >> 9;
        int rest = bid & 511;
        int c0 = (rest & 63) << 6;
        int r0 = (rest >> 6) << 7;
        transpose_tile128(w1, w1t, DIM, HID, e, r0, c0, smem);
        return;
    }
    // router: one wave per token (fused x->bf16 conversion)
    int t = (bid - TW1_BLKS) * 4 + (threadIdx.x >> 6);
    int lane = threadIdx.x & 63;
    const float4* xr = (const float4*)(x + (size_t)t * DIM);
    float acc[NEXP];
#pragma unroll
    for (int e = 0; e < NEXP; ++e) acc[e] = 0.f;
#pragma unroll
    for (int i = 0; i < 4; ++i) {
        int vidx = lane + i * 64;
        float4 v = xr[vidx];
        ushort4 o;
        o.x = f2bf(v.x); o.y = f2bf(v.y); o.z = f2bf(v.z); o.w = f2bf(v.w);
        ((ushort4*)xb)[(size_t)t * 256 + vidx] = o;
        const float4* wr = (const float4*)(rw + (size_t)vidx * 4 * NEXP);
        float xs[4] = {v.x, v.y, v.z, v.w};
#pragma unroll
        for (int j = 0; j < 4; ++j) {
            float4 wlo = wr[j * 2 + 0], whi = wr[j * 2 + 1];
            acc[0] += xs[j] * wlo.x; acc[1] += xs[j] * wlo.y;
            acc[2] += xs[j] * wlo.z; acc[3] += xs[j] * wlo.w;
            acc[4] += xs[j] * whi.x; acc[5] += xs[j] * whi.y;
            acc[6] += xs[j] * whi.z; acc[7] += xs[j] * whi.w;
        }
    }
#pragma unroll
    for (int e = 0; e < NEXP; ++e) {
#pragma unroll
        for (int off = 32; off; off >>= 1) acc[e] += __shfl_xor(acc[e], off);
    }
    if (lane == 0) {
        float l[NEXP];
#pragma unroll
        for (int e = 0; e < NEXP; ++e) l[e] = acc[e] + rb[e];
        float best = -1e30f; int bi = 0;
#pragma unroll
        for (int e = 0; e < NEXP; ++e) if (l[e] > best) { best = l[e]; bi = e; }
        float best2 = -1e30f; int bi2 = 0;
#pragma unroll
        for (int e = 0; e < NEXP; ++e) { if (e == bi) continue; if (l[e] > best2) { best2 = l[e]; bi2 = e; } }
        float w0 = 1.f / (1.f + expf(best2 - best));
        top_i[t * 2] = bi;  top_i[t * 2 + 1] = bi2;
        top_w[t * 2] = w0;  top_w[t * 2 + 1] = 1.f - w0;
        atomicAdd(&counts[bi], 1);
        atomicAdd(&counts[bi2], 1);
    }
}

// tile_start[e] = cumsum of ceil(counts[e]/128); tile_start[8] = total M-tiles
__global__ void scan_kernel(const int* __restrict__ counts, int* __restrict__ offsets,
                            int* __restrict__ tile_start) {
    if (threadIdx.x == 0) {
        int o = 0, t = 0;
        for (int e = 0; e < NEXP; ++e) {
            offsets[e] = o;
            tile_start[e] = t;
            t += (counts[e] + 127) >> 7;
            o += counts[e];
        }
        tile_start[NEXP] = t;
    }
}

__global__ __launch_bounds__(256) void assign_kernel(
    const int* __restrict__ top_i, const float* __restrict__ top_w,
    const int* __restrict__ offsets, int* __restrict__ cursors,
    int* __restrict__ row_token, float* __restrict__ row_w,
    int* __restrict__ slot_of) {
    int t = blockIdx.x * 256 + threadIdx.x;
    if (t >= T_TOK) return;
#pragma unroll
    for (int k = 0; k < 2; ++k) {
        int e = top_i[t * 2 + k];
        int s = atomicAdd(&cursors[e], 1);
        int g = offsets[e] + s;
        row_token[g] = t;
        row_w[g] = top_w[t * 2 + k];
        slot_of[t * 2 + k] = g;
    }
}

// ---------------- fused: GEMM1 + transpose w2 (round-8 verified GEMM body) ----------------

__global__ __launch_bounds__(256, 4) void g1_kernel(
    const unsigned short* __restrict__ xb,    // [T][DIM] bf16
    const unsigned short* __restrict__ w1t,   // [E][HID][DIM] bf16
    const float* __restrict__ b1,             // [E][HID]
    const int* __restrict__ row_token, const int* __restrict__ offsets,
    const int* __restrict__ counts, const int* __restrict__ ts,
    unsigned short* __restrict__ h_ws,        // [NSLOT][HID] bf16
    const float* __restrict__ w2, unsigned short* __restrict__ w2t) {
    __shared__ __align__(16) char smem[33280];
    const int bid = blockIdx.x;
    if (bid >= GRID1) {
        // w2 [E][HID][DIM] -> w2t [E][DIM][HID]: R=HID(32 r-tiles of 128), C=DIM(16 c-tiles)
        int r = bid - GRID1;
        int e = r >> 9;
        int rest = r & 511;
        int c0 = (rest & 15) << 6;
        int r0 = (rest >> 4) << 7;
        transpose_tile128(w2, w2t, HID, DIM, e, r0, c0, smem);
        return;
    }
    const int xcd = bid & 7, s = bid >> 3;    // s in [0, 4*MAXMT)
    if (s >= 4 * ts[NEXP]) return;
    int e = 0;
#pragma unroll
    for (int k = 1; k < NEXP; ++k) if (s >= 4 * ts[k]) e = k;
    const int ntile = ts[e + 1] - ts[e];
    const int local = s - 4 * ts[e];
    const int q = local / ntile;              // 0..3
    const int mt = local - q * ntile;
    const int nt = q * 8 + xcd;               // 0..31
    const int cnt = counts[e];
    const int goff = offsets[e];

    unsigned short (*As)[64] = (unsigned short (*)[64])smem;            // 16 KB
    unsigned short (*Bs)[64] = (unsigned short (*)[64])(smem + 16384);  // 16 KB

    const int tid = threadIdx.x, wid = tid >> 6, lane = tid & 63;
    const int wm = wid >> 1, wn = wid & 1;

    f32x4 acc[4][4];
#pragma unroll
    for (int i = 0; i < 4; ++i)
#pragma unroll
        for (int j = 0; j < 4; ++j) acc[i][j] = (f32x4){0.f, 0.f, 0.f, 0.f};

    const unsigned short* srcA[4];
    const unsigned short* srcB[4];
#pragma unroll
    for (int it = 0; it < 4; ++it) {
        int idx = it * 256 + tid;
        int r = idx >> 3, kg = idx & 7;
        int sk = kg ^ (r & 7);                 // swizzled source chunk
        int rr = mt * 128 + r;
        int tok = row_token[goff + (rr < cnt ? rr : 0)];
        srcA[it] = xb + (size_t)tok * DIM + sk * 8;
        srcB[it] = w1t + ((size_t)e * HID + nt * 128 + r) * DIM + sk * 8;
    }

    for (int t = 0; t < 16; ++t) {
        const int k0 = t * 64;
#pragma unroll
        for (int it = 0; it < 4; ++it) {
            __builtin_amdgcn_global_load_lds(AS1(srcA[it] + k0),
                AS3((char*)As + (it * 4 + wid) * 1024), 16, 0, 0);
            __builtin_amdgcn_global_load_lds(AS1(srcB[it] + k0),
                AS3((char*)Bs + (it * 4 + wid) * 1024), 16, 0, 0);
        }
        __syncthreads();                       // drains vmcnt: tile ready
#pragma unroll
        for (int kk = 0; kk < 2; ++kk) {
            bf16x8 a[4], b[4];
            int ch = (kk * 4 + (lane >> 4)) ^ (lane & 7);
#pragma unroll
            for (int i = 0; i < 4; ++i) {
                int row = wm * 64 + i * 16 + (lane & 15);
                a[i] = *(const bf16x8*)((const char*)As + row * 128 + ch * 16);
            }
#pragma unroll
            for (int i = 0; i < 4; ++i) {
                int row = wn * 64 + i * 16 + (lane & 15);
                b[i] = *(const bf16x8*)((const char*)Bs + row * 128 + ch * 16);
            }
#pragma unroll
            for (int i = 0; i < 4; ++i)
#pragma unroll
                for (int j = 0; j < 4; ++j)
                    acc[i][j] = mfma16(a[i], b[j], acc[i][j]);
        }
        __syncthreads();                       // all waves done reading before restage
    }

    if (mt * 128 + 128 <= cnt) {               // fast path: full tile
#pragma unroll
        for (int j = 0; j < 4; ++j) {
            int n = nt * 128 + wn * 64 + j * 16 + (lane & 15);
            float bias = b1[e * HID + n];
#pragma unroll
            for (int i = 0; i < 4; ++i) {
#pragma unroll
                for (int q2 = 0; q2 < 4; ++q2) {
                    int rr = mt * 128 + wm * 64 + i * 16 + (lane >> 4) * 4 + q2;
                    float v = fmaxf(acc[i][j][q2] + bias, 0.f);
                    h_ws[(size_t)(goff + rr) * HID + n] = f2bf(v);
                }
            }
        }
    } else {
#pragma unroll
        for (int j = 0; j < 4; ++j) {
            int n = nt * 128 + wn * 64 + j * 16 + (lane & 15);
            float bias = b1[e * HID + n];
#pragma unroll
            for (int i = 0; i < 4; ++i) {
#pragma unroll
                for (int q2 = 0; q2 < 4; ++q2) {
                    int rr = mt * 128 + wm * 64 + i * 16 + (lane >> 4) * 4 + q2;
                    if (rr < cnt) {
                        float v = fmaxf(acc[i][j][q2] + bias, 0.f);
                        h_ws[(size_t)(goff + rr) * HID + n] = f2bf(v);
                    }
                }
            }
        }
    }
}

// GEMM2 (split-K): y_part[ks][slot][n] = sum_{k in slice} h[slot][k] * w2t[e][n][k]
__global__ __launch_bounds__(256, 4) void gemm2_kernel(
    const unsigned short* __restrict__ h_ws,  // [NSLOT][HID] bf16
    const unsigned short* __restrict__ w2t,   // [E][DIM][HID] bf16
    const int* __restrict__ offsets, const int* __restrict__ counts,
    const int* __restrict__ ts,
    float* __restrict__ y_part) {             // [KSPLIT][NSLOT][DIM] f32
    const int bid = blockIdx.x;
    const int xcd = bid & 7, s = bid >> 3;    // s in [0, 2*MAXMT)
    if (s >= 2 * ts[NEXP]) return;
    int e = 0;
#pragma unroll
    for (int k = 1; k < NEXP; ++k) if (s >= 2 * ts[k]) e = k;
    const int ntile = ts[e + 1] - ts[e];
    const int local = s - 2 * ts[e];
    const int ks = local / ntile;             // 0..1
    const int mt = local - ks * ntile;
    const int nt = xcd;                       // 0..7
    const int cnt = counts[e];
    const int goff = offsets[e];

    __shared__ __align__(16) unsigned short As[128][64];
    __shared__ __align__(16) unsigned short Bs[128][64];

    const int tid = threadIdx.x, wid = tid >> 6, lane = tid & 63;
    const int wm = wid >> 1, wn = wid & 1;

    f32x4 acc[4][4];
#pragma unroll
    for (int i = 0; i < 4; ++i)
#pragma unroll
        for (int j = 0; j < 4; ++j) acc[i][j] = (f32x4){0.f, 0.f, 0.f, 0.f};

    const unsigned short* srcA[4];
    const unsigned short* srcB[4];
#pragma unroll
    for (int it = 0; it < 4; ++it) {
        int idx = it * 256 + tid;
        int r = idx >> 3, kg = idx & 7;
        int sk = kg ^ (r & 7);
        int rr = mt * 128 + r;
        int g = goff + (rr < cnt ? rr : 0);
        srcA[it] = h_ws + (size_t)g * HID + sk * 8;
        srcB[it] = w2t + ((size_t)e * DIM + nt * 128 + r) * HID + sk * 8;
    }

    const int kbase = ks * KS_LEN;
    for (int t = 0; t < KS_LEN / 64; ++t) {
        const int k0 = kbase + t * 64;
#pragma unroll
        for (int it = 0; it < 4; ++it) {
            __builtin_amdgcn_global_load_lds(AS1(srcA[it] + k0),
                AS3((char*)As + (it * 4 + wid) * 1024), 16, 0, 0);
            __builtin_amdgcn_global_load_lds(AS1(srcB[it] + k0),
                AS3((char*)Bs + (it * 4 + wid) * 1024), 16, 0, 0);
        }
        __syncthreads();
#pragma unroll
        for (int kk = 0; kk < 2; ++kk) {
            bf16x8 a[4], b[4];
            int ch = (kk * 4 + (lane >> 4)) ^ (lane & 7);
#pragma unroll
            for (int i = 0; i < 4; ++i) {
                int row = wm * 64 + i * 16 + (lane & 15);
                a[i] = *(const bf16x8*)((const char*)As + row * 128 + ch * 16);
            }
#pragma unroll
            for (int i = 0; i < 4; ++i) {
                int row = wn * 64 + i * 16 + (lane & 15);
                b[i] = *(const bf16x8*)((const char*)Bs + row * 128 + ch * 16);
            }
#pragma unroll
            for (int i = 0; i < 4; ++i)
#pragma unroll
                for (int j = 0; j < 4; ++j)
                    acc[i][j] = mfma16(a[i], b[j], acc[i][j]);
        }
        __syncthreads();
    }

    if (mt * 128 + 128 <= cnt) {               // fast path
#pragma unroll
        for (int j = 0; j < 4; ++j) {
            int n = nt * 128 + wn * 64 + j * 16 + (lane & 15);
#pragma unroll
            for (int i = 0; i < 4; ++i) {
#pragma unroll
                for (int q2 = 0; q2 < 4; ++q2) {
                    int rr = mt * 128 + wm * 64 + i * 16 + (lane >> 4) * 4 + q2;
                    y_part[((size_t)ks * NSLOT + goff + rr) * DIM + n] = acc[i][j][q2];
                }
            }
        }
    } else {
#pragma unroll
        for (int j = 0; j < 4; ++j) {
            int n = nt * 128 + wn * 64 + j * 16 + (lane & 15);
#pragma unroll
            for (int i = 0; i < 4; ++i) {
#pragma unroll
                for (int q2 = 0; q2 < 4; ++q2) {
                    int rr = mt * 128 + wm * 64 + i * 16 + (lane >> 4) * 4 + q2;
                    if (rr < cnt) {
                        y_part[((size_t)ks * NSLOT + goff + rr) * DIM + n] = acc[i][j][q2];
                    }
                }
            }
        }
    }
}

// out[t][d] = w0*(p0[s0]+p1[s0]+b2[e0]) + w1*(p0[s1]+p1[s1]+b2[e1])
__global__ __launch_bounds__(256) void combine_kernel(
    const float* __restrict__ y_part, const int* __restrict__ slot_of,
    const int* __restrict__ top_i, const float* __restrict__ top_w,
    const float* __restrict__ b2, float* __restrict__ out) {
    int i = blockIdx.x * 256 + threadIdx.x;    // over T*256 float4s
    int t = i >> 8, c = i & 255;
    int s0 = slot_of[t * 2], s1 = slot_of[t * 2 + 1];
    int e0 = top_i[t * 2],  e1 = top_i[t * 2 + 1];
    float w0 = top_w[t * 2], w1 = top_w[t * 2 + 1];
    const float4* P = (const float4*)y_part;
    float4 p00 = P[(size_t)s0 * 256 + c];
    float4 p01 = P[((size_t)NSLOT + s0) * 256 + c];
    float4 p10 = P[(size_t)s1 * 256 + c];
    float4 p11 = P[((size_t)NSLOT + s1) * 256 + c];
    float4 b0 = ((const float4*)b2)[e0 * 256 + c];
    float4 b1 = ((const float4*)b2)[e1 * 256 + c];
    float4 o;
    o.x = w0 * (p00.x + p01.x + b0.x) + w1 * (p10.x + p11.x + b1.x);
    o.y = w0 * (p00.y + p01.y + b0.y) + w1 * (p10.y + p11.y + b1.y);
    o.z = w0 * (p00.z + p01.z + b0.z) + w1 * (p10.z + p11.z + b1.z);
    o.w = w0 * (p00.w + p01.w + b0.w) + w1 * (p10.w + p11.w + b1.w);
    ((float4*)out)[i] = o;
}

// ---------------- launch ----------------

extern "C" void kernel_launch(void* const* d_in, const int* in_sizes, int n_in,
                              void* d_out, int out_size, void* d_ws, size_t ws_size,
                              hipStream_t stream) {
    const float* x   = (const float*)d_in[0];
    const float* rw  = (const float*)d_in[1];
    const float* rb  = (const float*)d_in[2];
    const float* w1  = (const float*)d_in[3];
    const float* b1  = (const float*)d_in[4];
    const float* w2  = (const float*)d_in[5];
    const float* b2  = (const float*)d_in[6];
    float* out = (float*)d_out;

    char* ws = (char*)d_ws;
    size_t off = 0;
    auto alloc = [&](size_t bytes) { size_t r = off; off = (off + bytes + 255) & ~(size_t)255; return r; };
    unsigned short* xb   = (unsigned short*)(ws + alloc((size_t)T_TOK * DIM * 2));
    unsigned short* w1t  = (unsigned short*)(ws + alloc((size_t)NEXP * DIM * HID * 2));  // 64 MB
    unsigned short* w2t  = (unsigned short*)(ws + alloc((size_t)NEXP * HID * DIM * 2));  // 64 MB
    unsigned short* h_ws = (unsigned short*)(ws + alloc((size_t)NSLOT * HID * 2));       // 64 MB
    int*   top_i         = (int*)(ws + alloc((size_t)NSLOT * 4));
    float* top_w         = (float*)(ws + alloc((size_t)NSLOT * 4));
    int*   slot_of       = (int*)(ws + alloc((size_t)NSLOT * 4));
    int*   row_token     = (int*)(ws + alloc((size_t)NSLOT * 4));
    float* row_w         = (float*)(ws + alloc((size_t)NSLOT * 4));
    char*  ctrl          = ws + alloc(256);
    int* counts     = (int*)(ctrl);
    int* cursors    = (int*)(ctrl + 64);
    int* offsets    = (int*)(ctrl + 128);
    int* tile_start = (int*)(ctrl + 192);      // 9 ints
    // y_part (2 x NSLOT x DIM f32 = 64 MB) aliases w1t: w1t is dead once g1 completes,
    // and gemm2/combine run strictly after g1 on the same stream.
    float* y_part = (float*)w1t;

    hipMemsetAsync(ctrl, 0, 256, stream);

    // fused: transpose w1 + router
    pre_kernel<<<TW1_BLKS + T_TOK / 4, 256, 0, stream>>>(w1, w1t, x, rw, rb, xb,
                                                         top_i, top_w, counts);
    scan_kernel<<<1, 64, 0, stream>>>(counts, offsets, tile_start);
    assign_kernel<<<T_TOK / 256, 256, 0, stream>>>(top_i, top_w, offsets, cursors,
                                                   row_token, row_w, slot_of);

    // fused: gemm1 + transpose w2 (w2t consumed only by gemm2, next launch)
    g1_kernel<<<GRID1 + TW2_BLKS, 256, 0, stream>>>(xb, w1t, b1, row_token, offsets,
                                                    counts, tile_start, h_ws, w2, w2t);
    gemm2_kernel<<<GRID2, 256, 0, stream>>>(h_ws, w2t, offsets, counts, tile_start, y_part);

    combine_kernel<<<T_TOK * 256 / 256, 256, 0, stream>>>(y_part, slot_of, top_i, top_w, b2, out);
}